// Round 8
// baseline (981.173 us; speedup 1.0000x reference)
//
#include <hip/hip_runtime.h>

typedef unsigned short u16;
typedef __attribute__((ext_vector_type(8))) short bfrag8;   // 8 x bf16 (4 VGPRs)
typedef __attribute__((ext_vector_type(4))) float f32x4;

// ---------- bf16 helpers ----------
__device__ __forceinline__ float b2f(u16 u){ union { unsigned ui; float f; } v; v.ui = ((unsigned)u) << 16; return v.f; }
__device__ __forceinline__ u16 f2b(float f){ union { float f; unsigned ui; } v; v.f = f; unsigned r = (v.ui + 0x7FFF + ((v.ui >> 16) & 1)) >> 16; return (u16)r; }

// ---------- async global->LDS, 16B per lane ----------
__device__ __forceinline__ void gl_lds16(const u16* g, u16* l){
  __builtin_amdgcn_global_load_lds(
      (const __attribute__((address_space(1))) unsigned*)g,
      (__attribute__((address_space(3))) unsigned*)l, 16, 0, 0);
}

// ---------- zero ----------
__global__ __launch_bounds__(256) void zero_f32(float* p, int n){
  int i = blockIdx.x*256 + threadIdx.x;
  if (i < n) p[i] = 0.f;
}

// ---------- split x (f32) -> xh, xl (bf16 planes), 8 elems/thread ----------
__global__ __launch_bounds__(256) void split_x(const float* __restrict__ x,
    u16* __restrict__ xh, u16* __restrict__ xl){
  size_t i = ((size_t)blockIdx.x*256 + threadIdx.x) * 8;
  float v[8];
  *(float4*)v       = *(const float4*)(x + i);
  *(float4*)(v + 4) = *(const float4*)(x + i + 4);
  u16 h[8], l[8];
  #pragma unroll
  for (int j = 0; j < 8; ++j){ u16 a = f2b(v[j]); h[j] = a; l[j] = f2b(v[j] - b2f(a)); }
  *(uint4*)(xh + i) = *(uint4*)h;
  *(uint4*)(xl + i) = *(uint4*)l;
}

// ---------- transpose + split: W (KxN f32) -> Th, Tl (NxK bf16) ----------
__global__ __launch_bounds__(256) void transpose_split(const float* __restrict__ W,
    u16* __restrict__ Th, u16* __restrict__ Tl, int K, int N){
  __shared__ float tile[32][33];
  int bx = blockIdx.x * 32, by = blockIdx.y * 32;
  int tx = threadIdx.x & 31, ty = threadIdx.x >> 5;
  #pragma unroll
  for (int i = 0; i < 32; i += 8) tile[ty+i][tx] = W[(size_t)(by+ty+i)*N + bx+tx];
  __syncthreads();
  #pragma unroll
  for (int i = 0; i < 32; i += 8){
    float v = tile[tx][ty+i];
    u16 h = f2b(v);
    Th[(size_t)(bx+ty+i)*K + by+tx] = h;
    Tl[(size_t)(bx+ty+i)*K + by+tx] = f2b(v - b2f(h));
  }
}

// ---------- transpose + downcast: W (KxN f32) -> Wt (NxK bf16) ----------
__global__ __launch_bounds__(256) void transpose_f2b(const float* __restrict__ W, u16* __restrict__ Wt, int K, int N){
  __shared__ u16 tile[32][33];
  int bx = blockIdx.x * 32, by = blockIdx.y * 32;
  int tx = threadIdx.x & 31, ty = threadIdx.x >> 5;
  #pragma unroll
  for (int i = 0; i < 32; i += 8) tile[ty+i][tx] = f2b(W[(size_t)(by+ty+i)*N + bx+tx]);
  __syncthreads();
  #pragma unroll
  for (int i = 0; i < 32; i += 8) Wt[(size_t)(bx+ty+i)*K + by+tx] = tile[tx][ty+i];
}

// ---------- plane GEMM: C = (Ah+Al)(Bh+Bl)^T approx, all bf16 planes ----------
// Counted-vmcnt double-buffered pipeline (T4, m201/m218 template):
//   STAGE(buf^1, t+1) -> s_waitcnt vmcnt(NSTG) (waits ONLY the current tile's
//   loads; prefetch stays in flight across the barrier) -> raw s_barrier ->
//   CMP(buf) -> raw s_barrier.  __syncthreads would drain vmcnt(0) (round-3
//   failure); raw s_barrier + counted wait is the fix.
// LDS layout per plane (u16 idx): off(row,k) = (k>>3)*1024 + row*8 + (k&7)
//   -> lane-linear for global_load_lds, conflict-free ds_read_b128 fragments.
// NPROD 3: hi*lo + lo*hi + hi*hi (bit-identical 2-split). NPROD 1: plain bf16.
// Epilogue: col<1024 -> Cq f32, col<2048 -> Ck f32, else Cv bf16.
template<int NPROD>
__global__ __launch_bounds__(256, (NPROD==3)?2:3) void gemm_planes(
    const u16* __restrict__ Ah, const u16* __restrict__ Al, int lda,
    const u16* __restrict__ Bh, const u16* __restrict__ Bl, int bn_off,
    const float* __restrict__ bias,
    float* __restrict__ Cq, float* __restrict__ Ck, u16* __restrict__ Cv, int K)
{
  constexpr int NS = (NPROD==3) ? 2 : 1;
  __shared__ __align__(16) u16 As[2*NS*4096];   // [dbuf][plane][kchunk*1024+row*8+k7]
  __shared__ __align__(16) u16 Bs[2*NS*4096];
  int tid = threadIdx.x, lane = tid & 63, wave = tid >> 6;
  int wm = wave >> 1, wn = wave & 1;
  int bm = blockIdx.y * 128, bn = blockIdx.x * 128;
  f32x4 acc[4][4];
  #pragma unroll
  for (int i=0;i<4;i++)
    #pragma unroll
    for (int j=0;j<4;j++)
      #pragma unroll
      for (int r=0;r<4;r++) acc[i][j][r] = 0.f;
  int mr = lane & 15, g = lane >> 4;
  int srow = (wave & 1)*64 + lane;
  int kc1 = (wave >> 1)*8;      // u16 col offset of first kchunk
  int kc2 = kc1 + 16;           // +2 chunks
  const u16* gA0 = Ah + (size_t)(bm + srow)*lda;
  const u16* gA1 = Al + (size_t)(bm + srow)*lda;
  const u16* gB0 = Bh + (size_t)(bn_off + bn + srow)*K;
  const u16* gB1 = Bl + (size_t)(bn_off + bn + srow)*K;

#define STG(BUF, KO) { \
    u16* aB = As + (BUF)*NS*4096;  u16* bB = Bs + (BUF)*NS*4096; \
    gl_lds16(gA0 + (KO) + kc1, aB + wave*512); \
    gl_lds16(gA0 + (KO) + kc2, aB + (wave+4)*512); \
    gl_lds16(gB0 + (KO) + kc1, bB + wave*512); \
    gl_lds16(gB0 + (KO) + kc2, bB + (wave+4)*512); \
    if constexpr (NS > 1){ \
      gl_lds16(gA1 + (KO) + kc1, aB + 4096 + wave*512); \
      gl_lds16(gA1 + (KO) + kc2, aB + 4096 + (wave+4)*512); \
      gl_lds16(gB1 + (KO) + kc1, bB + 4096 + wave*512); \
      gl_lds16(gB1 + (KO) + kc2, bB + 4096 + (wave+4)*512); } }

#define MMACC(sa,sb) \
    { _Pragma("unroll") for (int i=0;i<4;i++){ _Pragma("unroll") for (int j=0;j<4;j++){ \
        acc[i][j] = __builtin_amdgcn_mfma_f32_16x16x32_bf16(af[sa][i], bf[sb][j], acc[i][j], 0, 0, 0); } } }

#define CMP(BUF) { \
    const u16* aB = As + (BUF)*NS*4096;  const u16* bB = Bs + (BUF)*NS*4096; \
    bfrag8 af[NS][4], bf[NS][4]; \
    _Pragma("unroll") \
    for (int s=0;s<NS;s++){ \
      _Pragma("unroll") \
      for (int i=0;i<4;i++) af[s][i] = *(const bfrag8*)(aB + s*4096 + g*1024 + (wm*64 + i*16 + mr)*8); \
      _Pragma("unroll") \
      for (int j=0;j<4;j++) bf[s][j] = *(const bfrag8*)(bB + s*4096 + g*1024 + (wn*64 + j*16 + mr)*8); } \
    if constexpr (NPROD == 3){ MMACC(0,1) MMACC(1,0) } \
    MMACC(0,0) }

  STG(0, 0)
  int cur = 0;
  for (int k0 = 0; k0 < K - 32; k0 += 32) {
    STG(cur^1, k0 + 32)                          // prefetch next tile
    if constexpr (NS > 1) asm volatile("s_waitcnt vmcnt(8)" ::: "memory");
    else                  asm volatile("s_waitcnt vmcnt(4)" ::: "memory");
    __builtin_amdgcn_sched_barrier(0);
    __builtin_amdgcn_s_barrier();                // current tile visible to all waves
    __builtin_amdgcn_sched_barrier(0);
    CMP(cur)                                     // compute; prefetch stays in flight
    __builtin_amdgcn_s_barrier();                // reads done before next overwrite
    cur ^= 1;
  }
  asm volatile("s_waitcnt vmcnt(0)" ::: "memory");
  __builtin_amdgcn_sched_barrier(0);
  __builtin_amdgcn_s_barrier();
  __builtin_amdgcn_sched_barrier(0);
  CMP(cur)
#undef STG
#undef CMP
#undef MMACC

  #pragma unroll
  for (int i=0;i<4;i++){
    #pragma unroll
    for (int j=0;j<4;j++){
      int col = bn_off + bn + wn*64 + j*16 + (lane & 15);
      float bv = bias[col];
      #pragma unroll
      for (int r=0;r<4;r++){
        int row = bm + wm*64 + i*16 + (lane>>4)*4 + r;
        float val = acc[i][j][r] + bv;
        if (col < 1024)      Cq[(size_t)row*1024 + col]        = val;
        else if (col < 2048) Ck[(size_t)row*1024 + (col-1024)] = val;
        else                 Cv[(size_t)row*1024 + (col-2048)] = f2b(val);
      }
    }
  }
}

// ---------- plain bf16 GEMM: C f32 = A(u16, lda) @ Bt(u16 NxK)^T + bias ----------
// Same counted-vmcnt double-buffered pipeline (NSTG=4).
__global__ __launch_bounds__(256, 3) void gemm_b16(const u16* __restrict__ A, int lda,
    const u16* __restrict__ Bt, const float* __restrict__ bias, float* __restrict__ C, int N, int K)
{
  __shared__ __align__(16) u16 As[2*4096];
  __shared__ __align__(16) u16 Bs[2*4096];
  int tid = threadIdx.x, lane = tid & 63, wave = tid >> 6;
  int wm = wave >> 1, wn = wave & 1;
  int bm = blockIdx.y * 128, bn = blockIdx.x * 128;
  f32x4 acc[4][4];
  #pragma unroll
  for (int i=0;i<4;i++)
    #pragma unroll
    for (int j=0;j<4;j++)
      #pragma unroll
      for (int r=0;r<4;r++) acc[i][j][r] = 0.f;
  int mr = lane & 15, g = lane >> 4;
  int srow = (wave & 1)*64 + lane;
  int kc1 = (wave >> 1)*8, kc2 = kc1 + 16;
  const u16* gA = A  + (size_t)(bm + srow)*lda;
  const u16* gB = Bt + (size_t)(bn + srow)*K;

#define STG_B(BUF, KO) { \
    u16* aB = As + (BUF)*4096;  u16* bB = Bs + (BUF)*4096; \
    gl_lds16(gA + (KO) + kc1, aB + wave*512); \
    gl_lds16(gA + (KO) + kc2, aB + (wave+4)*512); \
    gl_lds16(gB + (KO) + kc1, bB + wave*512); \
    gl_lds16(gB + (KO) + kc2, bB + (wave+4)*512); }

#define CMP_B(BUF) { \
    const u16* aB = As + (BUF)*4096;  const u16* bB = Bs + (BUF)*4096; \
    bfrag8 af[4], bf[4]; \
    _Pragma("unroll") \
    for (int i=0;i<4;i++) af[i] = *(const bfrag8*)(aB + g*1024 + (wm*64 + i*16 + mr)*8); \
    _Pragma("unroll") \
    for (int j=0;j<4;j++) bf[j] = *(const bfrag8*)(bB + g*1024 + (wn*64 + j*16 + mr)*8); \
    _Pragma("unroll") \
    for (int i=0;i<4;i++){ \
      _Pragma("unroll") \
      for (int j=0;j<4;j++) \
        acc[i][j] = __builtin_amdgcn_mfma_f32_16x16x32_bf16(af[i], bf[j], acc[i][j], 0, 0, 0); } }

  STG_B(0, 0)
  int cur = 0;
  for (int k0 = 0; k0 < K - 32; k0 += 32) {
    STG_B(cur^1, k0 + 32)
    asm volatile("s_waitcnt vmcnt(4)" ::: "memory");
    __builtin_amdgcn_sched_barrier(0);
    __builtin_amdgcn_s_barrier();
    __builtin_amdgcn_sched_barrier(0);
    CMP_B(cur)
    __builtin_amdgcn_s_barrier();
    cur ^= 1;
  }
  asm volatile("s_waitcnt vmcnt(0)" ::: "memory");
  __builtin_amdgcn_sched_barrier(0);
  __builtin_amdgcn_s_barrier();
  __builtin_amdgcn_sched_barrier(0);
  CMP_B(cur)
#undef STG_B
#undef CMP_B

  #pragma unroll
  for (int i=0;i<4;i++){
    #pragma unroll
    for (int j=0;j<4;j++){
      int col = bn + wn*64 + j*16 + (lane & 15);
      float bv = bias[col];
      #pragma unroll
      for (int r=0;r<4;r++){
        int row = bm + wm*64 + i*16 + (lane>>4)*4 + r;
        C[(size_t)row*N + col] = acc[i][j][r] + bv;
      }
    }
  }
}

// ---------- per-d constants ----------
struct __align__(16) ConsT { int b1; float sg1; int b2; float sg2; };

// 4-lanes-per-token feature computation: tloc = lane&15 (token), g = lane>>4 (d-group).
// After this, every one of the 4 lanes holds full cs1/cs2/pm sums; poly4 = its 4 p's; prf = all 8.
#define FEATS_COMPUTE(TILE, TOKA)                                                \
  float sq = 0.f;                                                                \
  _Pragma("unroll")                                                              \
  for (int dd = 0; dd < 16; ++dd){ float u = TILE[(TOKA)*65 + g*16 + dd]; sq += u*u; } \
  sq += __shfl_xor(sq, 16); sq += __shfl_xor(sq, 32);                            \
  float sc = 1.f / fmaxf(sqrtf(sq), 1e-6f);                                      \
  float cs1[16], cs2[16], pm[8];                                                 \
  _Pragma("unroll") for (int p=0;p<16;p++){ cs1[p]=0.f; cs2[p]=0.f; }            \
  _Pragma("unroll") for (int m=0;m<8;m++) pm[m]=0.f;                             \
  _Pragma("unroll")                                                              \
  for (int dd = 0; dd < 16; ++dd){                                               \
    int d = g*16 + dd;                                                           \
    float un = TILE[(TOKA)*65 + d] * sc;                                         \
    ConsT cc = cons[d];                                                          \
    float v1 = un*cc.sg1, v2 = un*cc.sg2;                                        \
    _Pragma("unroll")                                                            \
    for (int p=0;p<16;p++){ cs1[p] += (cc.b1==p)?v1:0.f; cs2[p] += (cc.b2==p)?v2:0.f; } \
    _Pragma("unroll")                                                            \
    for (int m=0;m<8;m++) pm[m] += un * oms[d*8 + m];                            \
  }                                                                              \
  _Pragma("unroll")                                                              \
  for (int p=0;p<16;p++){ cs1[p] += __shfl_xor(cs1[p],16); cs1[p] += __shfl_xor(cs1[p],32); \
                          cs2[p] += __shfl_xor(cs2[p],16); cs2[p] += __shfl_xor(cs2[p],32); } \
  _Pragma("unroll")                                                              \
  for (int m=0;m<8;m++){ pm[m] += __shfl_xor(pm[m],16); pm[m] += __shfl_xor(pm[m],32); } \
  float poly4[4];                                                                \
  _Pragma("unroll")                                                              \
  for (int pi=0;pi<4;pi++){ int p = g*4 + pi; float s = 0.f;                     \
    _Pragma("unroll") for (int a=0;a<16;a++) s += cs1[a]*cs2[(p-a)&15];          \
    poly4[pi] = s * 0.25f; }                                                     \
  float prf[8];                                                                  \
  _Pragma("unroll")                                                              \
  for (int m=0;m<8;m++){ float e = fminf(fmaxf(pm[m]*sqrt2s - s_node, -10.f), 10.f); \
    prf[m] = expf(e) * pscale; }

// ---------- K-path: features + kv^T (64d x 128f) via MFMA + ksum ----------
__global__ __launch_bounds__(256) void kfeat_kv(const float* __restrict__ kf, const u16* __restrict__ vb,
    const float* __restrict__ omega, const float* __restrict__ qn, const float* __restrict__ qw,
    const int* __restrict__ h1, const int* __restrict__ s1,
    const int* __restrict__ h2, const int* __restrict__ s2,
    float* __restrict__ kvT, float* __restrict__ ksum)
{
  __shared__ float ktile[64*65];                 // 16.6 KB (f32 k, feature input)
  __shared__ __align__(16) u16 vtile[64*64];     //  8 KB  (bf16 V, [tok][d])
  __shared__ __align__(16) u16 featT[128*72];    // 18 KB  (bf16 feat^T, [f][tok])
  __shared__ float oms[64*8];
  __shared__ ConsT cons[64];
  int tid = threadIdx.x, lane = tid & 63, wave = tid >> 6;
  int bh = blockIdx.y, b = bh >> 4, h = bh & 15;
  int chunk = blockIdx.x;                        // 0..7, 512 tokens each
  if (tid < 64) {
    ConsT c; c.b1 = h1[tid]; c.sg1 = (float)s1[tid]; c.b2 = h2[tid]; c.sg2 = (float)s2[tid];
    cons[tid] = c;
  }
  for (int i = tid; i < 512; i += 256) oms[i] = omega[h*512 + i];
  float s_node = qn[0];
  float sqrt2s = sqrtf(2.f * fmaxf(s_node, 0.f));
  float pscale = 0.35355339059327373f * sqrtf(fmaxf(qw[0], 0.f));
  int tloc = lane & 15, g = lane >> 4;
  int tokA = wave*16 + tloc;
  int wm = wave >> 1, wn = wave & 1;             // MFMA wave grid: M=128f (2), N=64d (2)
  int mr = lane & 15, kq8 = (lane >> 4) * 8;
  f32x4 acc[4][2];                               // 4 m-frags x 2 n-frags
  #pragma unroll
  for (int i=0;i<4;i++)
    #pragma unroll
    for (int jn=0;jn<2;jn++)
      #pragma unroll
      for (int r=0;r<4;r++) acc[i][jn][r] = 0.f;
  float kacc[32];
  #pragma unroll
  for (int j=0;j<32;j++) kacc[j] = 0.f;
  for (int sub = 0; sub < 8; ++sub) {
    int base = chunk*512 + sub*64;
    __syncthreads();                             // prior MFMA reads done before tile overwrite
    for (int idx = tid; idx < 4096; idx += 256) {
      int t = idx >> 6, d = idx & 63;
      ktile[t*65 + d] = kf[(size_t)(b*4096 + base + t)*1024 + h*64 + d];
    }
    for (int slot = tid; slot < 512; slot += 256) {
      int t = slot >> 3, o = (slot & 7) * 8;
      *(uint4*)(&vtile[t*64 + o]) = *(const uint4*)(&vb[(size_t)(b*4096 + base + t)*1024 + h*64 + o]);
    }
    __syncthreads();                             // tiles ready
    {
      FEATS_COMPUTE(ktile, tokA)
      #pragma unroll
      for (int pi=0;pi<4;pi++){
        #pragma unroll
        for (int m=0;m<8;m++){
          int f = (g*4 + pi)*8 + m;
          float v = poly4[pi]*prf[m];
          featT[f*72 + tokA] = f2b(v);
          v += __shfl_xor(v,1); v += __shfl_xor(v,2); v += __shfl_xor(v,4); v += __shfl_xor(v,8);
          if (tloc == 0) kacc[pi*8 + m] += v;
        }
      }
    }
    __syncthreads();                             // featT ready
    #pragma unroll
    for (int k0 = 0; k0 < 64; k0 += 32) {
      bfrag8 af[4];
      #pragma unroll
      for (int i=0;i<4;i++) af[i] = *(const bfrag8*)(&featT[(wm*64 + i*16 + mr)*72 + k0 + kq8]);
      #pragma unroll
      for (int jn=0;jn<2;jn++){
        int d = wn*32 + jn*16 + mr;
        short tmp[8];
        #pragma unroll
        for (int j=0;j<8;j++) tmp[j] = (short)vtile[(k0 + kq8 + j)*64 + d];
        bfrag8 bf = *(bfrag8*)tmp;
        #pragma unroll
        for (int i=0;i<4;i++)
          acc[i][jn] = __builtin_amdgcn_mfma_f32_16x16x32_bf16(af[i], bf, acc[i][jn], 0, 0, 0);
      }
    }
  }
  // epilogue: kv^T[d][f] += acc   (C/D: col=lane&15, row=(lane>>4)*4+reg)
  #pragma unroll
  for (int i=0;i<4;i++){
    #pragma unroll
    for (int jn=0;jn<2;jn++){
      int d = wn*32 + jn*16 + (lane & 15);
      #pragma unroll
      for (int r=0;r<4;r++){
        int f = wm*64 + i*16 + (lane>>4)*4 + r;
        atomicAdd(&kvT[((size_t)bh*64 + d)*128 + f], acc[i][jn][r]);
      }
    }
  }
  if (tloc == 0){
    #pragma unroll
    for (int j=0;j<32;j++) atomicAdd(&ksum[bh*128 + g*32 + j], kacc[j]);
  }
}

// ---------- Q-path: features + nrm (f32) + ctx via MFMA; writes attn bf16 into kf region ----------
__global__ __launch_bounds__(256) void qfeat_ctx(const float* __restrict__ qf,
    const float* __restrict__ omega, const float* __restrict__ qn, const float* __restrict__ qw,
    const int* __restrict__ h1, const int* __restrict__ s1,
    const int* __restrict__ h2, const int* __restrict__ s2,
    const float* __restrict__ kvT, const float* __restrict__ ksum,
    u16* __restrict__ attn)                      // row stride 2048 u16 (kf reuse)
{
  __shared__ float qtile[64*65];                 // 16.6 KB
  __shared__ __align__(16) u16 feat[64*136];     // 17.4 KB [tok][f]
  __shared__ __align__(16) u16 kvsb0[64*136];    // 17.4 KB [d][f] split-hi
  __shared__ __align__(16) u16 kvsb1[64*136];    // 17.4 KB [d][f] split-lo
  __shared__ float ksums[128];
  __shared__ float nrm_s[64];
  __shared__ float oms[64*8];
  __shared__ ConsT cons[64];
  int tid = threadIdx.x, lane = tid & 63, wave = tid >> 6;
  int bh = blockIdx.y, b = bh >> 4, h = bh & 15;
  int chunk = blockIdx.x;                        // 0..7, 512 tokens each
  if (tid < 64) {
    ConsT c; c.b1 = h1[tid]; c.sg1 = (float)s1[tid]; c.b2 = h2[tid]; c.sg2 = (float)s2[tid];
    cons[tid] = c;
  }
  for (int i = tid; i < 512; i += 256) oms[i] = omega[h*512 + i];
  for (int idx = tid; idx < 8192; idx += 256) {
    int d = idx >> 7, f = idx & 127;
    float v = kvT[((size_t)bh*64 + d)*128 + f];
    u16 b0 = f2b(v);
    kvsb0[d*136 + f] = b0;
    kvsb1[d*136 + f] = f2b(v - b2f(b0));
  }
  if (tid < 128) ksums[tid] = ksum[bh*128 + tid];
  float s_node = qn[0];
  float sqrt2s = sqrtf(2.f * fmaxf(s_node, 0.f));
  float pscale = 0.35355339059327373f * sqrtf(fmaxf(qw[0], 0.f));
  int tloc = lane & 15, g = lane >> 4;
  int tokA = wave*16 + tloc;
  int mr = lane & 15, kq8 = (lane >> 4) * 8;
  for (int sub = 0; sub < 8; ++sub) {
    int base = chunk*512 + sub*64;
    for (int idx = tid; idx < 4096; idx += 256) {
      int t = idx >> 6, d = idx & 63;
      qtile[t*65 + d] = qf[(size_t)(b*4096 + base + t)*1024 + h*64 + d];
    }
    __syncthreads();                             // qtile ready; prior MFMA feat reads done
    {
      FEATS_COMPUTE(qtile, tokA)
      float nv = 0.f;
      #pragma unroll
      for (int pi=0;pi<4;pi++){
        #pragma unroll
        for (int m=0;m<8;m++){
          int f = (g*4 + pi)*8 + m;
          float v = poly4[pi]*prf[m];
          feat[tokA*136 + f] = f2b(v);
          nv += v * ksums[f];
        }
      }
      nv += __shfl_xor(nv, 16); nv += __shfl_xor(nv, 32);
      if (lane < 16) nrm_s[tokA] = nv;
    }
    __syncthreads();                             // feat + nrm ready
    // ctx(16tok x 64d per wave) = feat @ kv  (kv 2-split)
    f32x4 cacc[4];
    #pragma unroll
    for (int jn=0;jn<4;jn++)
      #pragma unroll
      for (int r=0;r<4;r++) cacc[jn][r] = 0.f;
    #pragma unroll
    for (int k0 = 0; k0 < 128; k0 += 32) {
      bfrag8 af = *(const bfrag8*)(&feat[(wave*16 + mr)*136 + k0 + kq8]);
      #pragma unroll
      for (int jn=0;jn<4;jn++){
        int d = jn*16 + mr;
        bfrag8 b0 = *(const bfrag8*)(&kvsb0[d*136 + k0 + kq8]);
        cacc[jn] = __builtin_amdgcn_mfma_f32_16x16x32_bf16(af, b0, cacc[jn], 0, 0, 0);
        bfrag8 b1 = *(const bfrag8*)(&kvsb1[d*136 + k0 + kq8]);
        cacc[jn] = __builtin_amdgcn_mfma_f32_16x16x32_bf16(af, b1, cacc[jn], 0, 0, 0);
      }
    }
    #pragma unroll
    for (int jn=0;jn<4;jn++){
      int d = jn*16 + (lane & 15);
      #pragma unroll
      for (int r=0;r<4;r++){
        int row = (lane>>4)*4 + r;
        float nrm = nrm_s[wave*16 + row];
        int tok = base + wave*16 + row;
        attn[(size_t)(b*4096 + tok)*2048 + h*64 + d] = f2b(cacc[jn][r] / fmaxf(nrm, 1e-4f));
      }
    }
  }
}

// ---------- launch ----------
extern "C" void kernel_launch(void* const* d_in, const int* in_sizes, int n_in,
                              void* d_out, int out_size, void* d_ws, size_t ws_size,
                              hipStream_t stream)
{
  const float* x     = (const float*)d_in[0];
  const float* qkv_w = (const float*)d_in[1];
  const float* qkv_b = (const float*)d_in[2];
  const float* out_w = (const float*)d_in[3];
  const float* out_b = (const float*)d_in[4];
  const float* omega = (const float*)d_in[5];
  const float* qn    = (const float*)d_in[6];
  const float* qw    = (const float*)d_in[7];
  const int* h1 = (const int*)d_in[8];
  const int* s1 = (const int*)d_in[9];
  const int* h2 = (const int*)d_in[10];
  const int* s2 = (const int*)d_in[11];

  // ws (~240 MB): qf f32 | kf f32 (later attn bf16, lda 2048) | vb bf16 |
  //               xh bf16 | xl bf16 | wTh bf16 | wTl bf16 | wT2 bf16 | kvT f32 | ksum f32
  const size_t SZ_Q  = (size_t)16384*1024*4;   // 64 MB
  const size_t SZ_K  = (size_t)16384*1024*4;   // 64 MB
  const size_t SZ_V  = (size_t)16384*1024*2;   // 32 MB
  const size_t SZ_XH = (size_t)16384*1024*2;   // 32 MB
  const size_t SZ_XL = (size_t)16384*1024*2;   // 32 MB
  const size_t SZ_WH = (size_t)3072*1024*2;    //  6 MB
  const size_t SZ_WL = (size_t)3072*1024*2;    //  6 MB
  const size_t SZ_W2 = (size_t)1024*1024*2;    //  2 MB
  const size_t SZ_KV = (size_t)64*64*128*4;    //  2 MB
  char* ws = (char*)d_ws;
  float* qf  = (float*)ws;
  float* kf  = (float*)(ws + SZ_Q);
  u16*   vb  = (u16*)  (ws + SZ_Q + SZ_K);
  u16*   xh  = (u16*)  (ws + SZ_Q + SZ_K + SZ_V);
  u16*   xl  = (u16*)  (ws + SZ_Q + SZ_K + SZ_V + SZ_XH);
  u16*   wTh = (u16*)  (ws + SZ_Q + SZ_K + SZ_V + SZ_XH + SZ_XL);
  u16*   wTl = (u16*)  (ws + SZ_Q + SZ_K + SZ_V + SZ_XH + SZ_XL + SZ_WH);
  u16*   wT2 = (u16*)  (ws + SZ_Q + SZ_K + SZ_V + SZ_XH + SZ_XL + SZ_WH + SZ_WL);
  float* kvT = (float*)(ws + SZ_Q + SZ_K + SZ_V + SZ_XH + SZ_XL + SZ_WH + SZ_WL + SZ_W2);
  float* ksp = (float*)(ws + SZ_Q + SZ_K + SZ_V + SZ_XH + SZ_XL + SZ_WH + SZ_WL + SZ_W2 + SZ_KV);

  int nz = (int)((SZ_KV + (size_t)64*128*4) / 4);
  zero_f32<<<(nz+255)/256, 256, 0, stream>>>(kvT, nz);
  split_x<<<(16384*1024/8)/256, 256, 0, stream>>>(x, xh, xl);
  transpose_split<<<dim3(3072/32, 1024/32), 256, 0, stream>>>(qkv_w, wTh, wTl, 1024, 3072);
  transpose_f2b<<<dim3(1024/32, 1024/32), 256, 0, stream>>>(out_w, wT2, 1024, 1024);
  // q,k (cols 0..2047): 2-split, 3 products
  gemm_planes<3><<<dim3(16, 128), 256, 0, stream>>>(xh, xl, 1024, wTh, wTl, 0, qkv_b, qf, kf, vb, 1024);
  // v (cols 2048..3071): plain bf16
  gemm_planes<1><<<dim3(8, 128), 256, 0, stream>>>(xh, xl, 1024, wTh, wTl, 2048, qkv_b, qf, kf, vb, 1024);
  kfeat_kv<<<dim3(8, 64), 256, 0, stream>>>(kf, vb, omega, qn, qw, h1, s1, h2, s2, kvT, ksp);
  qfeat_ctx<<<dim3(8, 64), 256, 0, stream>>>(qf, omega, qn, qw, h1, s1, h2, s2, kvT, ksp, (u16*)kf);
  // out = attn @ out_w + out_b (plain bf16; attn rows have stride 2048 u16)
  gemm_b16<<<dim3(8, 128), 256, 0, stream>>>((const u16*)kf, 2048, wT2, out_b, (float*)d_out, 1024, 1024);
}

// Round 9
// 956.742 us; speedup vs baseline: 1.0255x; 1.0255x over previous
//
#include <hip/hip_runtime.h>

typedef unsigned short u16;
typedef __attribute__((ext_vector_type(8))) short bfrag8;   // 8 x bf16 (4 VGPRs)
typedef __attribute__((ext_vector_type(4))) float f32x4;

// ---------- bf16 helpers ----------
__device__ __forceinline__ float b2f(u16 u){ union { unsigned ui; float f; } v; v.ui = ((unsigned)u) << 16; return v.f; }
__device__ __forceinline__ u16 f2b(float f){ union { float f; unsigned ui; } v; v.f = f; unsigned r = (v.ui + 0x7FFF + ((v.ui >> 16) & 1)) >> 16; return (u16)r; }

// ---------- async global->LDS, 16B per lane ----------
__device__ __forceinline__ void gl_lds16(const u16* g, u16* l){
  __builtin_amdgcn_global_load_lds(
      (const __attribute__((address_space(1))) unsigned*)g,
      (__attribute__((address_space(3))) unsigned*)l, 16, 0, 0);
}

// ---------- bijective XCD-aware block swizzle (T1) ----------
// Default dispatch round-robins consecutive block ids across the 8 XCDs, so
// blocks sharing an A-row-panel land on different L2s. Remap so each XCD gets
// a contiguous chunk of row-panels (its B working set then fits its 4MB L2).
// Requires nwg % 8 == 0 (all GEMM grids here are 1024 or 2048).
__device__ __forceinline__ void xcd_swz(int& bx, int& by){
  int nx = gridDim.x, nwg = nx * gridDim.y;
  int orig = blockIdx.y * nx + blockIdx.x;
  int q = nwg >> 3;
  int nw = (orig & 7) * q + (orig >> 3);
  bx = nw % nx;  by = nw / nx;
}

// ---------- zero ----------
__global__ __launch_bounds__(256) void zero_f32(float* p, int n){
  int i = blockIdx.x*256 + threadIdx.x;
  if (i < n) p[i] = 0.f;
}

// ---------- split x (f32) -> xh, xl (bf16 planes), 8 elems/thread ----------
__global__ __launch_bounds__(256) void split_x(const float* __restrict__ x,
    u16* __restrict__ xh, u16* __restrict__ xl){
  size_t i = ((size_t)blockIdx.x*256 + threadIdx.x) * 8;
  float v[8];
  *(float4*)v       = *(const float4*)(x + i);
  *(float4*)(v + 4) = *(const float4*)(x + i + 4);
  u16 h[8], l[8];
  #pragma unroll
  for (int j = 0; j < 8; ++j){ u16 a = f2b(v[j]); h[j] = a; l[j] = f2b(v[j] - b2f(a)); }
  *(uint4*)(xh + i) = *(uint4*)h;
  *(uint4*)(xl + i) = *(uint4*)l;
}

// ---------- transpose + split: W (KxN f32) -> Th, Tl (NxK bf16) ----------
__global__ __launch_bounds__(256) void transpose_split(const float* __restrict__ W,
    u16* __restrict__ Th, u16* __restrict__ Tl, int K, int N){
  __shared__ float tile[32][33];
  int bx = blockIdx.x * 32, by = blockIdx.y * 32;
  int tx = threadIdx.x & 31, ty = threadIdx.x >> 5;
  #pragma unroll
  for (int i = 0; i < 32; i += 8) tile[ty+i][tx] = W[(size_t)(by+ty+i)*N + bx+tx];
  __syncthreads();
  #pragma unroll
  for (int i = 0; i < 32; i += 8){
    float v = tile[tx][ty+i];
    u16 h = f2b(v);
    Th[(size_t)(bx+ty+i)*K + by+tx] = h;
    Tl[(size_t)(bx+ty+i)*K + by+tx] = f2b(v - b2f(h));
  }
}

// ---------- transpose + downcast: W (KxN f32) -> Wt (NxK bf16) ----------
__global__ __launch_bounds__(256) void transpose_f2b(const float* __restrict__ W, u16* __restrict__ Wt, int K, int N){
  __shared__ u16 tile[32][33];
  int bx = blockIdx.x * 32, by = blockIdx.y * 32;
  int tx = threadIdx.x & 31, ty = threadIdx.x >> 5;
  #pragma unroll
  for (int i = 0; i < 32; i += 8) tile[ty+i][tx] = f2b(W[(size_t)(by+ty+i)*N + bx+tx]);
  __syncthreads();
  #pragma unroll
  for (int i = 0; i < 32; i += 8) Wt[(size_t)(bx+ty+i)*K + by+tx] = tile[tx][ty+i];
}

// ---------- plane GEMM: C = (Ah+Al)(Bh+Bl)^T approx, all bf16 planes ----------
// Round-7 measured-best structure: BK=32, single-buffered, 2 barriers/K-step,
// __launch_bounds__(256,3). Schedule variants (dbuf, BK=64, counted vmcnt)
// all measured neutral-to-worse (rounds 3,5,8) — do not touch the K-loop.
// LDS layout per plane (u16 idx): off(row,k) = (k>>3)*1024 + row*8 + (k&7)
//   -> lane-linear for global_load_lds, conflict-free ds_read_b128 fragments.
// NPROD 3: hi*lo + lo*hi + hi*hi (2-split). NPROD 1: plain bf16.
// One dispatch covers 1024 output cols (grid 8x128) selected by bn_off.
// Epilogue: col<1024 -> Cq f32, col<2048 -> Ck f32, else Cv bf16.
template<int NPROD>
__global__ __launch_bounds__(256, 3) void gemm_planes(
    const u16* __restrict__ Ah, const u16* __restrict__ Al, int lda,
    const u16* __restrict__ Bh, const u16* __restrict__ Bl, int bn_off,
    const float* __restrict__ bias,
    float* __restrict__ Cq, float* __restrict__ Ck, u16* __restrict__ Cv, int K)
{
  constexpr int NS = (NPROD==3) ? 2 : 1;
  __shared__ __align__(16) u16 As[NS*4096];
  __shared__ __align__(16) u16 Bs[NS*4096];
  int tid = threadIdx.x, lane = tid & 63, wave = tid >> 6;
  int wm = wave >> 1, wn = wave & 1;
  int bx, by;  xcd_swz(bx, by);
  int bm = by * 128, bn = bx * 128;
  f32x4 acc[4][4];
  #pragma unroll
  for (int i=0;i<4;i++)
    #pragma unroll
    for (int j=0;j<4;j++)
      #pragma unroll
      for (int r=0;r<4;r++) acc[i][j][r] = 0.f;
  int mr = lane & 15, g = lane >> 4;
  // staging geometry: wave w fills LDS regions w and w+4 (512 u16 each) per plane.
  int srow = (wave & 1)*64 + lane;
  int kc1 = (wave >> 1)*8;      // u16 col offset of first kchunk
  int kc2 = kc1 + 16;           // +2 chunks
  const u16* gA0 = Ah + (size_t)(bm + srow)*lda;
  const u16* gA1 = Al + (size_t)(bm + srow)*lda;
  const u16* gB0 = Bh + (size_t)(bn_off + bn + srow)*K;
  const u16* gB1 = Bl + (size_t)(bn_off + bn + srow)*K;
  u16* dA1 = &As[wave*512];  u16* dA2 = &As[(wave+4)*512];
  u16* dB1 = &Bs[wave*512];  u16* dB2 = &Bs[(wave+4)*512];

  for (int k0 = 0; k0 < K; k0 += 32) {
    gl_lds16(gA0 + k0 + kc1, dA1);
    gl_lds16(gA0 + k0 + kc2, dA2);
    gl_lds16(gB0 + k0 + kc1, dB1);
    gl_lds16(gB0 + k0 + kc2, dB2);
    if constexpr (NS > 1){
      gl_lds16(gA1 + k0 + kc1, dA1 + 4096);
      gl_lds16(gA1 + k0 + kc2, dA2 + 4096);
      gl_lds16(gB1 + k0 + kc1, dB1 + 4096);
      gl_lds16(gB1 + k0 + kc2, dB2 + 4096);
    }
    __syncthreads();                         // drain vmcnt + barrier: tiles ready
    bfrag8 af[NS][4], bf[NS][4];
    #pragma unroll
    for (int s=0;s<NS;s++){
      #pragma unroll
      for (int i=0;i<4;i++) af[s][i] = *(const bfrag8*)(&As[s*4096 + g*1024 + (wm*64 + i*16 + mr)*8]);
      #pragma unroll
      for (int j=0;j<4;j++) bf[s][j] = *(const bfrag8*)(&Bs[s*4096 + g*1024 + (wn*64 + j*16 + mr)*8]);
    }
#define MM(sa,sb) \
    { _Pragma("unroll") for (int i=0;i<4;i++){ _Pragma("unroll") for (int j=0;j<4;j++){ \
        acc[i][j] = __builtin_amdgcn_mfma_f32_16x16x32_bf16(af[sa][i], bf[sb][j], acc[i][j], 0, 0, 0); } } }
    if constexpr (NPROD == 3){ MM(0,1) MM(1,0) }
    MM(0,0)
#undef MM
    __syncthreads();                         // all reads done before next overwrite
  }
  #pragma unroll
  for (int i=0;i<4;i++){
    #pragma unroll
    for (int j=0;j<4;j++){
      int col = bn_off + bn + wn*64 + j*16 + (lane & 15);
      float bv = bias[col];
      #pragma unroll
      for (int r=0;r<4;r++){
        int row = bm + wm*64 + i*16 + (lane>>4)*4 + r;
        float val = acc[i][j][r] + bv;
        if (col < 1024)      Cq[(size_t)row*1024 + col]        = val;
        else if (col < 2048) Ck[(size_t)row*1024 + (col-1024)] = val;
        else                 Cv[(size_t)row*1024 + (col-2048)] = f2b(val);
      }
    }
  }
}

// ---------- plain bf16 GEMM: C f32 = A(u16, lda) @ Bt(u16 NxK)^T + bias ----------
// Round-7 structure + XCD swizzle.
__global__ __launch_bounds__(256, 3) void gemm_b16(const u16* __restrict__ A, int lda,
    const u16* __restrict__ Bt, const float* __restrict__ bias, float* __restrict__ C, int N, int K)
{
  __shared__ __align__(16) u16 As[4096];
  __shared__ __align__(16) u16 Bs[4096];
  int tid = threadIdx.x, lane = tid & 63, wave = tid >> 6;
  int wm = wave >> 1, wn = wave & 1;
  int bx, by;  xcd_swz(bx, by);
  int bm = by * 128, bn = bx * 128;
  f32x4 acc[4][4];
  #pragma unroll
  for (int i=0;i<4;i++)
    #pragma unroll
    for (int j=0;j<4;j++)
      #pragma unroll
      for (int r=0;r<4;r++) acc[i][j][r] = 0.f;
  int mr = lane & 15, g = lane >> 4;
  int srow = (wave & 1)*64 + lane;
  int kc1 = (wave >> 1)*8, kc2 = kc1 + 16;
  const u16* gA = A  + (size_t)(bm + srow)*lda;
  const u16* gB = Bt + (size_t)(bn + srow)*K;
  u16* dA1 = &As[wave*512];  u16* dA2 = &As[(wave+4)*512];
  u16* dB1 = &Bs[wave*512];  u16* dB2 = &Bs[(wave+4)*512];
  for (int k0 = 0; k0 < K; k0 += 32) {
    gl_lds16(gA + k0 + kc1, dA1);
    gl_lds16(gA + k0 + kc2, dA2);
    gl_lds16(gB + k0 + kc1, dB1);
    gl_lds16(gB + k0 + kc2, dB2);
    __syncthreads();
    bfrag8 af[4], bf[4];
    #pragma unroll
    for (int i=0;i<4;i++) af[i] = *(const bfrag8*)(&As[g*1024 + (wm*64 + i*16 + mr)*8]);
    #pragma unroll
    for (int j=0;j<4;j++) bf[j] = *(const bfrag8*)(&Bs[g*1024 + (wn*64 + j*16 + mr)*8]);
    #pragma unroll
    for (int i=0;i<4;i++)
      #pragma unroll
      for (int j=0;j<4;j++)
        acc[i][j] = __builtin_amdgcn_mfma_f32_16x16x32_bf16(af[i], bf[j], acc[i][j], 0, 0, 0);
    __syncthreads();
  }
  #pragma unroll
  for (int i=0;i<4;i++){
    #pragma unroll
    for (int j=0;j<4;j++){
      int col = bn + wn*64 + j*16 + (lane & 15);
      float bv = bias[col];
      #pragma unroll
      for (int r=0;r<4;r++){
        int row = bm + wm*64 + i*16 + (lane>>4)*4 + r;
        C[(size_t)row*N + col] = acc[i][j][r] + bv;
      }
    }
  }
}

// ---------- per-d constants ----------
struct __align__(16) ConsT { int b1; float sg1; int b2; float sg2; };

// 4-lanes-per-token feature computation: tloc = lane&15 (token), g = lane>>4 (d-group).
// After this, every one of the 4 lanes holds full cs1/cs2/pm sums; poly4 = its 4 p's; prf = all 8.
#define FEATS_COMPUTE(TILE, TOKA)                                                \
  float sq = 0.f;                                                                \
  _Pragma("unroll")                                                              \
  for (int dd = 0; dd < 16; ++dd){ float u = TILE[(TOKA)*65 + g*16 + dd]; sq += u*u; } \
  sq += __shfl_xor(sq, 16); sq += __shfl_xor(sq, 32);                            \
  float sc = 1.f / fmaxf(sqrtf(sq), 1e-6f);                                      \
  float cs1[16], cs2[16], pm[8];                                                 \
  _Pragma("unroll") for (int p=0;p<16;p++){ cs1[p]=0.f; cs2[p]=0.f; }            \
  _Pragma("unroll") for (int m=0;m<8;m++) pm[m]=0.f;                             \
  _Pragma("unroll")                                                              \
  for (int dd = 0; dd < 16; ++dd){                                               \
    int d = g*16 + dd;                                                           \
    float un = TILE[(TOKA)*65 + d] * sc;                                         \
    ConsT cc = cons[d];                                                          \
    float v1 = un*cc.sg1, v2 = un*cc.sg2;                                        \
    _Pragma("unroll")                                                            \
    for (int p=0;p<16;p++){ cs1[p] += (cc.b1==p)?v1:0.f; cs2[p] += (cc.b2==p)?v2:0.f; } \
    _Pragma("unroll")                                                            \
    for (int m=0;m<8;m++) pm[m] += un * oms[d*8 + m];                            \
  }                                                                              \
  _Pragma("unroll")                                                              \
  for (int p=0;p<16;p++){ cs1[p] += __shfl_xor(cs1[p],16); cs1[p] += __shfl_xor(cs1[p],32); \
                          cs2[p] += __shfl_xor(cs2[p],16); cs2[p] += __shfl_xor(cs2[p],32); } \
  _Pragma("unroll")                                                              \
  for (int m=0;m<8;m++){ pm[m] += __shfl_xor(pm[m],16); pm[m] += __shfl_xor(pm[m],32); } \
  float poly4[4];                                                                \
  _Pragma("unroll")                                                              \
  for (int pi=0;pi<4;pi++){ int p = g*4 + pi; float s = 0.f;                     \
    _Pragma("unroll") for (int a=0;a<16;a++) s += cs1[a]*cs2[(p-a)&15];          \
    poly4[pi] = s * 0.25f; }                                                     \
  float prf[8];                                                                  \
  _Pragma("unroll")                                                              \
  for (int m=0;m<8;m++){ float e = fminf(fmaxf(pm[m]*sqrt2s - s_node, -10.f), 10.f); \
    prf[m] = expf(e) * pscale; }

// ---------- K-path: features + kv^T (64d x 128f) via MFMA + ksum ----------
__global__ __launch_bounds__(256) void kfeat_kv(const float* __restrict__ kf, const u16* __restrict__ vb,
    const float* __restrict__ omega, const float* __restrict__ qn, const float* __restrict__ qw,
    const int* __restrict__ h1, const int* __restrict__ s1,
    const int* __restrict__ h2, const int* __restrict__ s2,
    float* __restrict__ kvT, float* __restrict__ ksum)
{
  __shared__ float ktile[64*65];                 // 16.6 KB (f32 k, feature input)
  __shared__ __align__(16) u16 vtile[64*64];     //  8 KB  (bf16 V, [tok][d])
  __shared__ __align__(16) u16 featT[128*72];    // 18 KB  (bf16 feat^T, [f][tok])
  __shared__ float oms[64*8];
  __shared__ ConsT cons[64];
  int tid = threadIdx.x, lane = tid & 63, wave = tid >> 6;
  int bh = blockIdx.y, b = bh >> 4, h = bh & 15;
  int chunk = blockIdx.x;                        // 0..7, 512 tokens each
  if (tid < 64) {
    ConsT c; c.b1 = h1[tid]; c.sg1 = (float)s1[tid]; c.b2 = h2[tid]; c.sg2 = (float)s2[tid];
    cons[tid] = c;
  }
  for (int i = tid; i < 512; i += 256) oms[i] = omega[h*512 + i];
  float s_node = qn[0];
  float sqrt2s = sqrtf(2.f * fmaxf(s_node, 0.f));
  float pscale = 0.35355339059327373f * sqrtf(fmaxf(qw[0], 0.f));
  int tloc = lane & 15, g = lane >> 4;
  int tokA = wave*16 + tloc;
  int wm = wave >> 1, wn = wave & 1;             // MFMA wave grid: M=128f (2), N=64d (2)
  int mr = lane & 15, kq8 = (lane >> 4) * 8;
  f32x4 acc[4][2];                               // 4 m-frags x 2 n-frags
  #pragma unroll
  for (int i=0;i<4;i++)
    #pragma unroll
    for (int jn=0;jn<2;jn++)
      #pragma unroll
      for (int r=0;r<4;r++) acc[i][jn][r] = 0.f;
  float kacc[32];
  #pragma unroll
  for (int j=0;j<32;j++) kacc[j] = 0.f;
  for (int sub = 0; sub < 8; ++sub) {
    int base = chunk*512 + sub*64;
    __syncthreads();                             // prior MFMA reads done before tile overwrite
    for (int idx = tid; idx < 4096; idx += 256) {
      int t = idx >> 6, d = idx & 63;
      ktile[t*65 + d] = kf[(size_t)(b*4096 + base + t)*1024 + h*64 + d];
    }
    for (int slot = tid; slot < 512; slot += 256) {
      int t = slot >> 3, o = (slot & 7) * 8;
      *(uint4*)(&vtile[t*64 + o]) = *(const uint4*)(&vb[(size_t)(b*4096 + base + t)*1024 + h*64 + o]);
    }
    __syncthreads();                             // tiles ready
    {
      FEATS_COMPUTE(ktile, tokA)
      #pragma unroll
      for (int pi=0;pi<4;pi++){
        #pragma unroll
        for (int m=0;m<8;m++){
          int f = (g*4 + pi)*8 + m;
          float v = poly4[pi]*prf[m];
          featT[f*72 + tokA] = f2b(v);
          v += __shfl_xor(v,1); v += __shfl_xor(v,2); v += __shfl_xor(v,4); v += __shfl_xor(v,8);
          if (tloc == 0) kacc[pi*8 + m] += v;
        }
      }
    }
    __syncthreads();                             // featT ready
    #pragma unroll
    for (int k0 = 0; k0 < 64; k0 += 32) {
      bfrag8 af[4];
      #pragma unroll
      for (int i=0;i<4;i++) af[i] = *(const bfrag8*)(&featT[(wm*64 + i*16 + mr)*72 + k0 + kq8]);
      #pragma unroll
      for (int jn=0;jn<2;jn++){
        int d = wn*32 + jn*16 + mr;
        short tmp[8];
        #pragma unroll
        for (int j=0;j<8;j++) tmp[j] = (short)vtile[(k0 + kq8 + j)*64 + d];
        bfrag8 bf = *(bfrag8*)tmp;
        #pragma unroll
        for (int i=0;i<4;i++)
          acc[i][jn] = __builtin_amdgcn_mfma_f32_16x16x32_bf16(af[i], bf, acc[i][jn], 0, 0, 0);
      }
    }
  }
  // epilogue: kv^T[d][f] += acc   (C/D: col=lane&15, row=(lane>>4)*4+reg)
  #pragma unroll
  for (int i=0;i<4;i++){
    #pragma unroll
    for (int jn=0;jn<2;jn++){
      int d = wn*32 + jn*16 + (lane & 15);
      #pragma unroll
      for (int r=0;r<4;r++){
        int f = wm*64 + i*16 + (lane>>4)*4 + r;
        atomicAdd(&kvT[((size_t)bh*64 + d)*128 + f], acc[i][jn][r]);
      }
    }
  }
  if (tloc == 0){
    #pragma unroll
    for (int j=0;j<32;j++) atomicAdd(&ksum[bh*128 + g*32 + j], kacc[j]);
  }
}

// ---------- Q-path: features + nrm (f32) + ctx via MFMA; writes attn bf16 into kf region ----------
__global__ __launch_bounds__(256) void qfeat_ctx(const float* __restrict__ qf,
    const float* __restrict__ omega, const float* __restrict__ qn, const float* __restrict__ qw,
    const int* __restrict__ h1, const int* __restrict__ s1,
    const int* __restrict__ h2, const int* __restrict__ s2,
    const float* __restrict__ kvT, const float* __restrict__ ksum,
    u16* __restrict__ attn)                      // row stride 2048 u16 (kf reuse)
{
  __shared__ float qtile[64*65];                 // 16.6 KB
  __shared__ __align__(16) u16 feat[64*136];     // 17.4 KB [tok][f]
  __shared__ __align__(16) u16 kvsb0[64*136];    // 17.4 KB [d][f] split-hi
  __shared__ __align__(16) u16 kvsb1[64*136];    // 17.4 KB [d][f] split-lo
  __shared__ float ksums[128];
  __shared__ float nrm_s[64];
  __shared__ float oms[64*8];
  __shared__ ConsT cons[64];
  int tid = threadIdx.x, lane = tid & 63, wave = tid >> 6;
  int bh = blockIdx.y, b = bh >> 4, h = bh & 15;
  int chunk = blockIdx.x;                        // 0..7, 512 tokens each
  if (tid < 64) {
    ConsT c; c.b1 = h1[tid]; c.sg1 = (float)s1[tid]; c.b2 = h2[tid]; c.sg2 = (float)s2[tid];
    cons[tid] = c;
  }
  for (int i = tid; i < 512; i += 256) oms[i] = omega[h*512 + i];
  for (int idx = tid; idx < 8192; idx += 256) {
    int d = idx >> 7, f = idx & 127;
    float v = kvT[((size_t)bh*64 + d)*128 + f];
    u16 b0 = f2b(v);
    kvsb0[d*136 + f] = b0;
    kvsb1[d*136 + f] = f2b(v - b2f(b0));
  }
  if (tid < 128) ksums[tid] = ksum[bh*128 + tid];
  float s_node = qn[0];
  float sqrt2s = sqrtf(2.f * fmaxf(s_node, 0.f));
  float pscale = 0.35355339059327373f * sqrtf(fmaxf(qw[0], 0.f));
  int tloc = lane & 15, g = lane >> 4;
  int tokA = wave*16 + tloc;
  int mr = lane & 15, kq8 = (lane >> 4) * 8;
  for (int sub = 0; sub < 8; ++sub) {
    int base = chunk*512 + sub*64;
    for (int idx = tid; idx < 4096; idx += 256) {
      int t = idx >> 6, d = idx & 63;
      qtile[t*65 + d] = qf[(size_t)(b*4096 + base + t)*1024 + h*64 + d];
    }
    __syncthreads();                             // qtile ready; prior MFMA feat reads done
    {
      FEATS_COMPUTE(qtile, tokA)
      float nv = 0.f;
      #pragma unroll
      for (int pi=0;pi<4;pi++){
        #pragma unroll
        for (int m=0;m<8;m++){
          int f = (g*4 + pi)*8 + m;
          float v = poly4[pi]*prf[m];
          feat[tokA*136 + f] = f2b(v);
          nv += v * ksums[f];
        }
      }
      nv += __shfl_xor(nv, 16); nv += __shfl_xor(nv, 32);
      if (lane < 16) nrm_s[tokA] = nv;
    }
    __syncthreads();                             // feat + nrm ready
    // ctx(16tok x 64d per wave) = feat @ kv  (kv 2-split)
    f32x4 cacc[4];
    #pragma unroll
    for (int jn=0;jn<4;jn++)
      #pragma unroll
      for (int r=0;r<4;r++) cacc[jn][r] = 0.f;
    #pragma unroll
    for (int k0 = 0; k0 < 128; k0 += 32) {
      bfrag8 af = *(const bfrag8*)(&feat[(wave*16 + mr)*136 + k0 + kq8]);
      #pragma unroll
      for (int jn=0;jn<4;jn++){
        int d = jn*16 + mr;
        bfrag8 b0 = *(const bfrag8*)(&kvsb0[d*136 + k0 + kq8]);
        cacc[jn] = __builtin_amdgcn_mfma_f32_16x16x32_bf16(af, b0, cacc[jn], 0, 0, 0);
        bfrag8 b1 = *(const bfrag8*)(&kvsb1[d*136 + k0 + kq8]);
        cacc[jn] = __builtin_amdgcn_mfma_f32_16x16x32_bf16(af, b1, cacc[jn], 0, 0, 0);
      }
    }
    #pragma unroll
    for (int jn=0;jn<4;jn++){
      int d = jn*16 + (lane & 15);
      #pragma unroll
      for (int r=0;r<4;r++){
        int row = (lane>>4)*4 + r;
        float nrm = nrm_s[wave*16 + row];
        int tok = base + wave*16 + row;
        attn[(size_t)(b*4096 + tok)*2048 + h*64 + d] = f2b(cacc[jn][r] / fmaxf(nrm, 1e-4f));
      }
    }
  }
}

// ---------- launch ----------
extern "C" void kernel_launch(void* const* d_in, const int* in_sizes, int n_in,
                              void* d_out, int out_size, void* d_ws, size_t ws_size,
                              hipStream_t stream)
{
  const float* x     = (const float*)d_in[0];
  const float* qkv_w = (const float*)d_in[1];
  const float* qkv_b = (const float*)d_in[2];
  const float* out_w = (const float*)d_in[3];
  const float* out_b = (const float*)d_in[4];
  const float* omega = (const float*)d_in[5];
  const float* qn    = (const float*)d_in[6];
  const float* qw    = (const float*)d_in[7];
  const int* h1 = (const int*)d_in[8];
  const int* s1 = (const int*)d_in[9];
  const int* h2 = (const int*)d_in[10];
  const int* s2 = (const int*)d_in[11];

  // ws (~240 MB): qf f32 | kf f32 (later attn bf16, lda 2048) | vb bf16 |
  //               xh bf16 | xl bf16 | wTh bf16 | wTl bf16 | wT2 bf16 | kvT f32 | ksum f32
  const size_t SZ_Q  = (size_t)16384*1024*4;   // 64 MB
  const size_t SZ_K  = (size_t)16384*1024*4;   // 64 MB
  const size_t SZ_V  = (size_t)16384*1024*2;   // 32 MB
  const size_t SZ_XH = (size_t)16384*1024*2;   // 32 MB
  const size_t SZ_XL = (size_t)16384*1024*2;   // 32 MB
  const size_t SZ_WH = (size_t)3072*1024*2;    //  6 MB
  const size_t SZ_WL = (size_t)3072*1024*2;    //  6 MB
  const size_t SZ_W2 = (size_t)1024*1024*2;    //  2 MB
  const size_t SZ_KV = (size_t)64*64*128*4;    //  2 MB
  char* ws = (char*)d_ws;
  float* qf  = (float*)ws;
  float* kf  = (float*)(ws + SZ_Q);
  u16*   vb  = (u16*)  (ws + SZ_Q + SZ_K);
  u16*   xh  = (u16*)  (ws + SZ_Q + SZ_K + SZ_V);
  u16*   xl  = (u16*)  (ws + SZ_Q + SZ_K + SZ_V + SZ_XH);
  u16*   wTh = (u16*)  (ws + SZ_Q + SZ_K + SZ_V + SZ_XH + SZ_XL);
  u16*   wTl = (u16*)  (ws + SZ_Q + SZ_K + SZ_V + SZ_XH + SZ_XL + SZ_WH);
  u16*   wT2 = (u16*)  (ws + SZ_Q + SZ_K + SZ_V + SZ_XH + SZ_XL + SZ_WH + SZ_WL);
  float* kvT = (float*)(ws + SZ_Q + SZ_K + SZ_V + SZ_XH + SZ_XL + SZ_WH + SZ_WL + SZ_W2);
  float* ksp = (float*)(ws + SZ_Q + SZ_K + SZ_V + SZ_XH + SZ_XL + SZ_WH + SZ_WL + SZ_W2 + SZ_KV);

  int nz = (int)((SZ_KV + (size_t)64*128*4) / 4);
  zero_f32<<<(nz+255)/256, 256, 0, stream>>>(kvT, nz);
  split_x<<<(16384*1024/8)/256, 256, 0, stream>>>(x, xh, xl);
  transpose_split<<<dim3(3072/32, 1024/32), 256, 0, stream>>>(qkv_w, wTh, wTl, 1024, 3072);
  transpose_f2b<<<dim3(1024/32, 1024/32), 256, 0, stream>>>(out_w, wT2, 1024, 1024);
  // q (cols 0..1023), k (cols 1024..2047): 2-split, 3 products — separate dispatches
  // so each XCD's B working set (4 MB) fits its L2, and profiling sees each.
  gemm_planes<3><<<dim3(8, 128), 256, 0, stream>>>(xh, xl, 1024, wTh, wTl, 0,    qkv_b, qf, kf, vb, 1024);
  gemm_planes<3><<<dim3(8, 128), 256, 0, stream>>>(xh, xl, 1024, wTh, wTl, 1024, qkv_b, qf, kf, vb, 1024);
  // v (cols 2048..3071): plain bf16
  gemm_planes<1><<<dim3(8, 128), 256, 0, stream>>>(xh, xl, 1024, wTh, wTl, 2048, qkv_b, qf, kf, vb, 1024);
  kfeat_kv<<<dim3(8, 64), 256, 0, stream>>>(kf, vb, omega, qn, qw, h1, s1, h2, s2, kvT, ksp);
  qfeat_ctx<<<dim3(8, 64), 256, 0, stream>>>(qf, omega, qn, qw, h1, s1, h2, s2, kvT, ksp, (u16*)kf);
  // out = attn @ out_w + out_b (plain bf16; attn rows have stride 2048 u16)
  gemm_b16<<<dim3(8, 128), 256, 0, stream>>>((const u16*)kf, 2048, wT2, out_b, (float*)d_out, 1024, 1024);
}